// Round 5
// baseline (357.253 us; speedup 1.0000x reference)
//
#include <hip/hip_runtime.h>
#include <hip/hip_bf16.h>

#define B 16
#define N 1024
#define F_IN 64
#define H 256
#define ALPHA 0.2f

typedef __attribute__((ext_vector_type(8))) short short8;
typedef __attribute__((ext_vector_type(4))) float floatx4;

__device__ __forceinline__ unsigned rne_hi(float v) {
    unsigned b = __float_as_uint(v);
    return (b + 0x7FFFu + ((b >> 16) & 1u)) >> 16;
}
__device__ __forceinline__ float bf16val(unsigned hi) { return __uint_as_float(hi << 16); }

__device__ __forceinline__ floatx4 mfma16(short8 a, short8 b, floatx4 c) {
    return __builtin_amdgcn_mfma_f32_16x16x32_bf16(a, b, c, 0, 0, 0);
}

// LDS-only barrier: does NOT drain vmcnt — global->reg prefetches stay in flight.
__device__ __forceinline__ void sync_lds() {
    asm volatile("s_waitcnt lgkmcnt(0)\ns_barrier" ::: "memory");
}

// packed RNE f32x2 -> bf16x2 (v_cvt_pk_bf16_f32 on gfx950)
__device__ __forceinline__ unsigned pk2_bf16(float a, float b) {
    __hip_bfloat162 h2 = __float22bfloat162_rn(float2{a, b});
    union { __hip_bfloat162 h; unsigned u; } cvt;
    cvt.h = h2;
    return cvt.u;
}

// ---------------------------------------------------------------------------
// adj [B,N,N] f32 -> bitmask u32: mask32[(b*N+i)*32 + j/32]
__global__ void k_mask(const float* __restrict__ adj, unsigned* __restrict__ mask32) {
    const int lane = threadIdx.x & 63;
    const int wave = blockIdx.x * 4 + (threadIdx.x >> 6);
    const int nwaves = gridDim.x * 4;
    const int words = B * N * (N / 64);
    for (int w = wave; w < words; w += nwaves) {
        float v = adj[(size_t)w * 64 + lane];
        unsigned long long m = __ballot(v > 0.f);
        if (lane == 0) { mask32[2 * w] = (unsigned)m; mask32[2 * w + 1] = (unsigned)(m >> 32); }
    }
}

// ---------------------------------------------------------------------------
// blocks 0-31: W -> transposed split bf16 W_t[c][k]; blocks 32-33: wa = W@a
__global__ __launch_bounds__(256) void k_prep(const float* __restrict__ W0, const float* __restrict__ W1,
                                              const float* __restrict__ a10, const float* __restrict__ a20,
                                              const float* __restrict__ a11, const float* __restrict__ a21,
                                              ushort* __restrict__ wth, ushort* __restrict__ wtl,
                                              float* __restrict__ wa1, float* __restrict__ wa2) {
    __shared__ float ld[64][65];
    const int t = threadIdx.x;
    if (blockIdx.x >= 32) {
        const int l = blockIdx.x - 32;
        const float* W = l ? W1 : W0;
        const float* a1 = l ? a11 : a10;
        const float* a2 = l ? a21 : a20;
        float* a1s = &ld[0][0];
        float* a2s = &ld[32][0];
        a1s[t] = a1[t]; a2s[t] = a2[t];
        __syncthreads();
        float v1 = 0.f, v2 = 0.f;
        for (int c = 0; c < H; c += 4) {
            float4 w = *(const float4*)&W[t * H + c];
            v1 += w.x * a1s[c] + w.y * a1s[c + 1] + w.z * a1s[c + 2] + w.w * a1s[c + 3];
            v2 += w.x * a2s[c] + w.y * a2s[c + 1] + w.z * a2s[c + 2] + w.w * a2s[c + 3];
        }
        wa1[l * H + t] = v1;
        wa2[l * H + t] = v2;
        return;
    }
    const int l = blockIdx.x >> 4;
    const int kt = (blockIdx.x >> 2) & 3, ct = blockIdx.x & 3;
    const float* W = l ? W1 : W0;
#pragma unroll
    for (int e = 0; e < 16; e++) {
        int idx = t + 256 * e;
        int kl = idx >> 6, cl = idx & 63;
        ld[kl][cl] = W[(kt * 64 + kl) * H + ct * 64 + cl];
    }
    __syncthreads();
    ushort* oh = wth + l * H * H;
    ushort* ol = wtl + l * H * H;
#pragma unroll
    for (int e = 0; e < 16; e++) {
        int idx = t + 256 * e;
        int cl = idx >> 6, kl = idx & 63;
        float v = ld[kl][cl];
        unsigned hi = rne_hi(v);
        float lo = v - bf16val(hi);
        oh[(ct * 64 + cl) * H + kt * 64 + kl] = (ushort)hi;
        ol[(ct * 64 + cl) * H + kt * 64 + kl] = (ushort)rne_hi(lo);
    }
}

// ---------------------------------------------------------------------------
// embed: x = nf @ emb_W + b -> split bf16 row-major x_hi/x_lo [B*N][H]
#define EMB_ROWS 8
__global__ __launch_bounds__(256) void k_embed(const float* __restrict__ nf,
                                               const float* __restrict__ W,
                                               const float* __restrict__ bias,
                                               ushort* __restrict__ xhi, ushort* __restrict__ xlo) {
    __shared__ float nfs[F_IN][EMB_ROWS];
    const int row0 = blockIdx.x * EMB_ROWS;
    const int t = threadIdx.x;
    for (int idx = t; idx < EMB_ROWS * F_IN; idx += 256) {
        int r = idx >> 6, f = idx & 63;
        nfs[f][r] = nf[(row0 + r) * F_IN + f];
    }
    __syncthreads();
    const int c = t;
    float acc[EMB_ROWS];
    float bv = bias[c];
#pragma unroll
    for (int r = 0; r < EMB_ROWS; r++) acc[r] = bv;
    for (int f = 0; f < F_IN; f++) {
        float w = W[f * H + c];
        float4 n0 = *(const float4*)&nfs[f][0];
        float4 n1 = *(const float4*)&nfs[f][4];
        acc[0] += n0.x * w; acc[1] += n0.y * w; acc[2] += n0.z * w; acc[3] += n0.w * w;
        acc[4] += n1.x * w; acc[5] += n1.y * w; acc[6] += n1.z * w; acc[7] += n1.w * w;
    }
#pragma unroll
    for (int r = 0; r < EMB_ROWS; r++) {
        float v = acc[r];
        unsigned hi = rne_hi(v);
        xhi[(size_t)(row0 + r) * H + c] = (ushort)hi;
        xlo[(size_t)(row0 + r) * H + c] = (ushort)rne_hi(v - bf16val(hi));
    }
}

// ---------------------------------------------------------------------------
// h = x @ W (bf16x3 MFMA), fully register-resident: A and B(W, L2-hot) loaded
// global->reg with 1-deep prefetch, ZERO barriers in K-loop. Epilogue: LDS
// transpose -> 64B-contiguous h_t stores. chalf0/w0: exact s1/s2 + s2max.
__global__ __launch_bounds__(256, 4) void k_gemm(const ushort* __restrict__ xhi, const ushort* __restrict__ xlo,
                                                 const ushort* __restrict__ wth, const ushort* __restrict__ wtl,
                                                 const float* __restrict__ wa1, const float* __restrict__ wa2,
                                                 ushort* __restrict__ hth, ushort* __restrict__ htl,
                                                 float* __restrict__ s1, float* __restrict__ s2,
                                                 unsigned* __restrict__ s2maxkey) {
    __shared__ ushort trh[128][40];         // [c_local][row_local], 80B stride
    __shared__ ushort trl[128][40];
    const int lin = blockIdx.x;
    const int rc = lin >> 1, chalf = lin & 1;
    const int row0 = rc * 32;
    const int t = threadIdx.x;
    const int lane = t & 63, w = t >> 6;
    const int l15 = lane & 15, quad = lane >> 4;
    const int nb = 2 * w;

    const ushort* wthh = wth + (size_t)(chalf * 128) * H;
    const ushort* wtlh = wtl + (size_t)(chalf * 128) * H;
    const ushort* b0h = wthh + (size_t)(nb * 16 + l15) * H + quad * 8;
    const ushort* b1h = wthh + (size_t)((nb + 1) * 16 + l15) * H + quad * 8;
    const ushort* b0l = wtlh + (size_t)(nb * 16 + l15) * H + quad * 8;
    const ushort* b1l = wtlh + (size_t)((nb + 1) * 16 + l15) * H + quad * 8;
    const ushort* ah0 = xhi + (size_t)(row0 + l15) * H + quad * 8;
    const ushort* al0 = xlo + (size_t)(row0 + l15) * H + quad * 8;
    const ushort* ah1 = xhi + (size_t)(row0 + 16 + l15) * H + quad * 8;
    const ushort* al1 = xlo + (size_t)(row0 + 16 + l15) * H + quad * 8;

    floatx4 acc[2][2];
    floatx4 z = {0.f, 0.f, 0.f, 0.f};
    acc[0][0] = z; acc[0][1] = z; acc[1][0] = z; acc[1][1] = z;
    float sp1a = 0.f, sp2a = 0.f, sp1b = 0.f, sp2b = 0.f;

    short8 A0h = *(const short8*)ah0;
    short8 A0l = *(const short8*)al0;
    short8 A1h = *(const short8*)ah1;
    short8 A1l = *(const short8*)al1;
    short8 Bh0 = *(const short8*)b0h;
    short8 Bh1 = *(const short8*)b1h;
    short8 Bl0 = *(const short8*)b0l;
    short8 Bl1 = *(const short8*)b1l;

#pragma unroll
    for (int ks = 0; ks < 8; ks++) {
        short8 nA0h = A0h, nA0l = A0l, nA1h = A1h, nA1l = A1l;
        short8 nBh0 = Bh0, nBh1 = Bh1, nBl0 = Bl0, nBl1 = Bl1;
        if (ks < 7) {
            const int k0n = (ks + 1) * 32;
            nA0h = *(const short8*)(ah0 + k0n);
            nA0l = *(const short8*)(al0 + k0n);
            nA1h = *(const short8*)(ah1 + k0n);
            nA1l = *(const short8*)(al1 + k0n);
            nBh0 = *(const short8*)(b0h + k0n);
            nBh1 = *(const short8*)(b1h + k0n);
            nBl0 = *(const short8*)(b0l + k0n);
            nBl1 = *(const short8*)(b1l + k0n);
        }
        acc[0][0] = mfma16(A0h, Bh0, acc[0][0]);
        acc[0][0] = mfma16(A0h, Bl0, acc[0][0]);
        acc[0][0] = mfma16(A0l, Bh0, acc[0][0]);
        acc[0][1] = mfma16(A0h, Bh1, acc[0][1]);
        acc[0][1] = mfma16(A0h, Bl1, acc[0][1]);
        acc[0][1] = mfma16(A0l, Bh1, acc[0][1]);
        acc[1][0] = mfma16(A1h, Bh0, acc[1][0]);
        acc[1][0] = mfma16(A1h, Bl0, acc[1][0]);
        acc[1][0] = mfma16(A1l, Bh0, acc[1][0]);
        acc[1][1] = mfma16(A1h, Bh1, acc[1][1]);
        acc[1][1] = mfma16(A1h, Bl1, acc[1][1]);
        acc[1][1] = mfma16(A1l, Bh1, acc[1][1]);
        if (chalf == 0 && w == 0) {
            float4 w1a = *(const float4*)(wa1 + ks * 32 + quad * 8);
            float4 w1b = *(const float4*)(wa1 + ks * 32 + quad * 8 + 4);
            float4 w2a = *(const float4*)(wa2 + ks * 32 + quad * 8);
            float4 w2b = *(const float4*)(wa2 + ks * 32 + quad * 8 + 4);
            float wv1[8] = {w1a.x, w1a.y, w1a.z, w1a.w, w1b.x, w1b.y, w1b.z, w1b.w};
            float wv2[8] = {w2a.x, w2a.y, w2a.z, w2a.w, w2b.x, w2b.y, w2b.z, w2b.w};
#pragma unroll
            for (int j = 0; j < 8; j++) {
                float xa = bf16val((ushort)A0h[j]) + bf16val((ushort)A0l[j]);
                float xb = bf16val((ushort)A1h[j]) + bf16val((ushort)A1l[j]);
                sp1a += xa * wv1[j]; sp2a += xa * wv2[j];
                sp1b += xb * wv1[j]; sp2b += xb * wv2[j];
            }
        }
        A0h = nA0h; A0l = nA0l; A1h = nA1h; A1l = nA1l;
        Bh0 = nBh0; Bh1 = nBh1; Bl0 = nBl0; Bl1 = nBl1;
    }

    // ---- epilogue: split-bf16 + LDS transpose -> contiguous h_t stores ----
#pragma unroll
    for (int rg = 0; rg < 2; rg++) {
        const int rl = rg * 16 + quad * 4;
#pragma unroll
        for (int n2 = 0; n2 < 2; n2++) {
            const int cl = (nb + n2) * 16 + l15;
            float v0 = acc[rg][n2][0], v1 = acc[rg][n2][1], v2 = acc[rg][n2][2], v3 = acc[rg][n2][3];
            unsigned h0 = rne_hi(v0), h1 = rne_hi(v1), h2 = rne_hi(v2), h3 = rne_hi(v3);
            ushort4 ph, pl;
            ph.x = (ushort)h0; ph.y = (ushort)h1; ph.z = (ushort)h2; ph.w = (ushort)h3;
            pl.x = (ushort)rne_hi(v0 - bf16val(h0));
            pl.y = (ushort)rne_hi(v1 - bf16val(h1));
            pl.z = (ushort)rne_hi(v2 - bf16val(h2));
            pl.w = (ushort)rne_hi(v3 - bf16val(h3));
            *(ushort4*)&trh[cl][rl] = ph;
            *(ushort4*)&trl[cl][rl] = pl;
        }
    }
    sync_lds();
    {
        const int bb = row0 >> 10;
        const int cl = t & 127, sel = t >> 7;
        const ushort(*tr)[40] = sel ? trl : trh;
        ushort* dst = (sel ? htl : hth) + ((size_t)(bb * H + chalf * 128 + cl) << 10) + (row0 & 1023);
        short8 r0 = *(const short8*)&tr[cl][0];
        short8 r1 = *(const short8*)&tr[cl][8];
        short8 r2 = *(const short8*)&tr[cl][16];
        short8 r3 = *(const short8*)&tr[cl][24];
        *(short8*)(dst) = r0;
        *(short8*)(dst + 8) = r1;
        *(short8*)(dst + 16) = r2;
        *(short8*)(dst + 24) = r3;
    }
    // ---- s1/s2 (exact x.wa) from wave 0 of chalf==0 blocks ----
    if (chalf == 0 && w == 0) {
        sp1a += __shfl_xor(sp1a, 16); sp1a += __shfl_xor(sp1a, 32);
        sp2a += __shfl_xor(sp2a, 16); sp2a += __shfl_xor(sp2a, 32);
        sp1b += __shfl_xor(sp1b, 16); sp1b += __shfl_xor(sp1b, 32);
        sp2b += __shfl_xor(sp2b, 16); sp2b += __shfl_xor(sp2b, 32);
        if (quad == 0) {
            s1[row0 + l15] = sp1a; s2[row0 + l15] = sp2a;
            s1[row0 + 16 + l15] = sp1b; s2[row0 + 16 + l15] = sp2b;
        }
        float m = fmaxf(sp2a, sp2b);
#pragma unroll
        for (int off = 1; off <= 8; off <<= 1) m = fmaxf(m, __shfl_xor(m, off));
        if (lane == 0) {
            unsigned bt = __float_as_uint(m);
            unsigned keyv = (bt & 0x80000000u) ? ~bt : (bt | 0x80000000u);
            atomicMax(&s2maxkey[row0 >> 10], keyv);
        }
    }
}

// ---------------------------------------------------------------------------
// GAT: out = relu((P/l) @ (h_hi+h_lo)). B-frags global->reg, depth-2 prefetch
// (no vmcnt drain at barriers); P via LDS dbuf + LDS-only barrier per jt.
template <int LAST>
__global__ __launch_bounds__(256, 2) void k_gat(const ushort* __restrict__ hth, const ushort* __restrict__ htl,
                                                const float* __restrict__ s1, const float* __restrict__ s2,
                                                const unsigned* __restrict__ mask32,
                                                const unsigned* __restrict__ s2maxkey,
                                                float* __restrict__ outf,
                                                ushort* __restrict__ oxhi, ushort* __restrict__ oxlo,
                                                float* __restrict__ psum, float* __restrict__ pmax) {
    __shared__ __align__(16) ushort p_s[2][2048];   // [rg][quad][l15][8us]
    __shared__ float l_s[64];
    const int lin = blockIdx.x;                     // 512 blocks
    const int xcd = lin & 7, sl = lin >> 3;
    const int b = xcd * 2 + (sl & 1);               // batch pinned to XCD pair
    const int chunk = (sl >> 1) & 15;
    const int chalf = sl >> 5;
    const int i0 = chunk * 64;
    const int t = threadIdx.x;
    const int lane = t & 63, w = t >> 6;            // wave w gens P rows rg=w
    const int l15 = lane & 15, quad = lane >> 4;
    const int nb = 2 * w;
    const int fo = quad * 128 + l15 * 8;

    unsigned key = s2maxkey[b];
    unsigned mb = (key & 0x80000000u) ? (key ^ 0x80000000u) : ~key;
    const float s2max = __uint_as_float(mb);

    const int i = i0 + w * 16 + l15;
    const float s1v = s1[b * N + i];
    const float tmx = s1v + s2max;
    const float mrow = fmaxf(tmx, ALPHA * tmx);
    const unsigned* mp = mask32 + (size_t)(b * N + i) * 32;
    const float* s2b = s2 + b * N;

    const ushort* hbh = hth + ((size_t)(b * H + chalf * 128) << 10);
    const ushort* hbl = htl + ((size_t)(b * H + chalf * 128) << 10);
    const ushort* pB0h = hbh + (((size_t)(nb * 16 + l15)) << 10) + quad * 8;
    const ushort* pB1h = hbh + (((size_t)((nb + 1) * 16 + l15)) << 10) + quad * 8;
    const ushort* pB0l = hbl + (((size_t)(nb * 16 + l15)) << 10) + quad * 8;
    const ushort* pB1l = hbl + (((size_t)((nb + 1) * 16 + l15)) << 10) + quad * 8;

    floatx4 acc[4][2];
    floatx4 z = {0.f, 0.f, 0.f, 0.f};
#pragma unroll
    for (int rg = 0; rg < 4; rg++) { acc[rg][0] = z; acc[rg][1] = z; }
    float lacc = 0.f;

    auto pgen = [&](unsigned mw, float4 sa, float4 sbv, int buf) {
        const unsigned mbyte = (mw >> (quad * 8)) & 0xffu;
        float sv[8] = {sa.x, sa.y, sa.z, sa.w, sbv.x, sbv.y, sbv.z, sbv.w};
        float pv[8];
#pragma unroll
        for (int j = 0; j < 8; j++) {
            float e1 = s1v + sv[j];
            e1 = fmaxf(e1, ALPHA * e1);
            float p = __expf(e1 - mrow);
            pv[j] = ((mbyte >> j) & 1u) ? p : 0.f;
        }
        uint4 pk;
        pk.x = pk2_bf16(pv[0], pv[1]);
        pk.y = pk2_bf16(pv[2], pv[3]);
        pk.z = pk2_bf16(pv[4], pv[5]);
        pk.w = pk2_bf16(pv[6], pv[7]);
        float ls = bf16val(pk.x & 0xffffu) + bf16val(pk.x >> 16)
                 + bf16val(pk.y & 0xffffu) + bf16val(pk.y >> 16)
                 + bf16val(pk.z & 0xffffu) + bf16val(pk.z >> 16)
                 + bf16val(pk.w & 0xffffu) + bf16val(pk.w >> 16);
        ls += __shfl_xor(ls, 16);
        ls += __shfl_xor(ls, 32);
        lacc += ls;
        *(uint4*)&p_s[buf][w * 512 + fo] = pk;
    };

    // prologue: P[0]; B regs for jt=0 (cur) and jt=1 (nxt); mask/s2 for pgen(1)
    {
        unsigned mw0 = mp[0];
        float4 sa0 = *(const float4*)(s2b + quad * 8);
        float4 sb0 = *(const float4*)(s2b + quad * 8 + 4);
        pgen(mw0, sa0, sb0, 0);
    }
    short8 cBh0 = *(const short8*)(pB0h);
    short8 cBh1 = *(const short8*)(pB1h);
    short8 cBl0 = *(const short8*)(pB0l);
    short8 cBl1 = *(const short8*)(pB1l);
    short8 nBh0 = *(const short8*)(pB0h + 32);
    short8 nBh1 = *(const short8*)(pB1h + 32);
    short8 nBl0 = *(const short8*)(pB0l + 32);
    short8 nBl1 = *(const short8*)(pB1l + 32);
    unsigned mw_n = mp[1];
    float4 sa_n = *(const float4*)(s2b + 32 + quad * 8);
    float4 sb_n = *(const float4*)(s2b + 32 + quad * 8 + 4);
    sync_lds();

#pragma unroll 2
    for (int jt = 0; jt < 32; jt++) {
        const int cur = jt & 1, nxt = cur ^ 1;
        // depth-2 B prefetch (clamped; stays in flight across the LDS barrier)
        const int j2 = (jt + 2 <= 31 ? jt + 2 : 31) * 32;
        short8 fBh0 = *(const short8*)(pB0h + j2);
        short8 fBh1 = *(const short8*)(pB1h + j2);
        short8 fBl0 = *(const short8*)(pB0l + j2);
        short8 fBl1 = *(const short8*)(pB1l + j2);
        short8 Ap[4];
#pragma unroll
        for (int rg = 0; rg < 4; rg++) Ap[rg] = *(const short8*)&p_s[cur][rg * 512 + fo];
#pragma unroll
        for (int rg = 0; rg < 4; rg++) {
            acc[rg][0] = mfma16(Ap[rg], cBh0, acc[rg][0]);
            acc[rg][0] = mfma16(Ap[rg], cBl0, acc[rg][0]);
            acc[rg][1] = mfma16(Ap[rg], cBh1, acc[rg][1]);
            acc[rg][1] = mfma16(Ap[rg], cBl1, acc[rg][1]);
        }
        if (jt < 31) {
            pgen(mw_n, sa_n, sb_n, nxt);
            const int jp = (jt + 2 <= 31) ? jt + 2 : 31;
            mw_n = mp[jp];
            sa_n = *(const float4*)(s2b + jp * 32 + quad * 8);
            sb_n = *(const float4*)(s2b + jp * 32 + quad * 8 + 4);
        }
        sync_lds();
        cBh0 = nBh0; cBh1 = nBh1; cBl0 = nBl0; cBl1 = nBl1;
        nBh0 = fBh0; nBh1 = fBh1; nBl0 = fBl0; nBl1 = fBl1;
    }
    if (quad == 0) l_s[w * 16 + l15] = lacc;
    sync_lds();

    float inv[4][4];
#pragma unroll
    for (int rg = 0; rg < 4; rg++)
#pragma unroll
        for (int r = 0; r < 4; r++) inv[rg][r] = 1.f / l_s[rg * 16 + quad * 4 + r];

    const size_t rbase = (size_t)b * N + i0;
    float colsum[2] = {0.f, 0.f}, colmax[2] = {-INFINITY, -INFINITY};
#pragma unroll
    for (int rg = 0; rg < 4; rg++)
#pragma unroll
        for (int n2 = 0; n2 < 2; n2++) {
            const int c = chalf * 128 + (nb + n2) * 16 + l15;
#pragma unroll
            for (int r = 0; r < 4; r++) {
                float v = fmaxf(acc[rg][n2][r] * inv[rg][r], 0.f);
                const size_t row = rbase + rg * 16 + quad * 4 + r;
                if (LAST) {
                    outf[row * H + c] = v;
                    colsum[n2] += v;
                    colmax[n2] = fmaxf(colmax[n2], v);
                } else {
                    unsigned hi = rne_hi(v);
                    oxhi[row * H + c] = (ushort)hi;
                    oxlo[row * H + c] = (ushort)rne_hi(v - bf16val(hi));
                }
            }
        }
    if (LAST) {
#pragma unroll
        for (int n2 = 0; n2 < 2; n2++) {
            float s = colsum[n2], m = colmax[n2];
            s += __shfl_xor(s, 16); s += __shfl_xor(s, 32);
            m = fmaxf(m, __shfl_xor(m, 16)); m = fmaxf(m, __shfl_xor(m, 32));
            if (quad == 0) {
                const int c = chalf * 128 + (nb + n2) * 16 + l15;
                psum[(b * 16 + chunk) * H + c] = s;
                pmax[(b * 16 + chunk) * H + c] = m;
            }
        }
    }
}

// ---------------------------------------------------------------------------
// finish mean+max over 16 chunk-partials, then 2-layer MLP -> g[b,:]
__global__ __launch_bounds__(256) void k_pool2(const float* __restrict__ psum,
                                               const float* __restrict__ pmax,
                                               const float* __restrict__ W1, const float* __restrict__ b1,
                                               const float* __restrict__ W2, const float* __restrict__ b2,
                                               float* __restrict__ gout) {
    __shared__ float g_s[H];
    __shared__ float t_s[H];
    const int b = blockIdx.x;
    const int c = threadIdx.x;
    float s = 0.f, m = -INFINITY;
#pragma unroll
    for (int ch = 0; ch < 16; ch++) {
        s += psum[(b * 16 + ch) * H + c];
        m = fmaxf(m, pmax[(b * 16 + ch) * H + c]);
    }
    g_s[c] = s * (1.f / N) + m;
    __syncthreads();
    float a = b1[c];
    for (int k = 0; k < H; k++) a += g_s[k] * W1[k * H + c];
    t_s[c] = fmaxf(a, 0.f);
    __syncthreads();
    float o = b2[c];
    for (int k = 0; k < H; k++) o += t_s[k] * W2[k * H + c];
    gout[b * H + c] = o;
}

// ---------------------------------------------------------------------------
extern "C" void kernel_launch(void* const* d_in, const int* in_sizes, int n_in,
                              void* d_out, int out_size, void* d_ws, size_t ws_size,
                              hipStream_t stream) {
    const float* nf    = (const float*)d_in[0];
    const float* adj   = (const float*)d_in[1];
    const float* emb_W = (const float*)d_in[2];
    const float* emb_b = (const float*)d_in[3];
    const float* W0    = (const float*)d_in[4];
    const float* a1_0  = (const float*)d_in[5];
    const float* a2_0  = (const float*)d_in[6];
    const float* W1    = (const float*)d_in[7];
    const float* a1_1  = (const float*)d_in[8];
    const float* a2_1  = (const float*)d_in[9];
    const float* gpW1  = (const float*)d_in[10];
    const float* gpb1  = (const float*)d_in[11];
    const float* gpW2  = (const float*)d_in[12];
    const float* gpb2  = (const float*)d_in[13];

    float* xout = (float*)d_out;
    float* gout = xout + B * N * H;

    char* w = (char*)d_ws;
    ushort* xhi      = (ushort*)(w);
    ushort* xlo      = (ushort*)(w + 8388608);
    ushort* hth      = (ushort*)(w + 16777216);
    ushort* htl      = (ushort*)(w + 25165824);
    unsigned* mask32 = (unsigned*)(w + 33554432);
    float* s1        = (float*)(w + 35651584);
    float* s2        = (float*)(w + 35717120);
    ushort* wth      = (ushort*)(w + 35782656);
    ushort* wtl      = (ushort*)(w + 36044800);
    float* wa1       = (float*)(w + 36306944);
    float* wa2       = (float*)(w + 36308992);
    unsigned* keys   = (unsigned*)(w + 36311040);
    // psum/pmax overlay xhi (dead after gemm<1>; written by gat<1>)
    float* psum      = (float*)(w);
    float* pmax      = (float*)(w + 262144);

    hipMemsetAsync(keys, 0, 128, stream);
    k_mask<<<1024, 256, 0, stream>>>(adj, mask32);
    k_prep<<<34, 256, 0, stream>>>(W0, W1, a1_0, a2_0, a1_1, a2_1, wth, wtl, wa1, wa2);
    k_embed<<<B * N / EMB_ROWS, 256, 0, stream>>>(nf, emb_W, emb_b, xhi, xlo);

    // layer 0
    k_gemm<<<B * N / 32 * 2, 256, 0, stream>>>(xhi, xlo, wth, wtl, wa1, wa2,
                                               hth, htl, s1, s2, keys);
    k_gat<0><<<512, 256, 0, stream>>>(hth, htl, s1, s2, mask32, keys,
                                      nullptr, xhi, xlo, nullptr, nullptr);

    // layer 1
    k_gemm<<<B * N / 32 * 2, 256, 0, stream>>>(xhi, xlo, wth + H * H, wtl + H * H, wa1 + H, wa2 + H,
                                               hth, htl, s1, s2, keys + 16);
    k_gat<1><<<512, 256, 0, stream>>>(hth, htl, s1, s2, mask32, keys + 16,
                                      xout, nullptr, nullptr, psum, pmax);

    // pooling MLP
    k_pool2<<<B, 256, 0, stream>>>(psum, pmax, gpW1, gpb1, gpW2, gpb2, gout);
}